// Round 12
// baseline (236.184 us; speedup 1.0000x reference)
//
#include <hip/hip_runtime.h>
#include <hip/hip_fp16.h>

// MHA with softmax over HEADS axis. R12 = R11 with the intrinsic name fixed
// (__builtin_amdgcn_mfma_f32_16x16x16f16 — legacy spelling, no underscore):
// - attn_ctx: P never touches LDS. QK computed TRANSPOSED (A=K,B=Q) so the
//   C/D layout (j=qd*4+r, i=l16) IS the A-operand layout of the K=16 MFMA;
//   P = (f16)(exp(st)*IDn) stays in registers, PV uses the K=16 MFMA with
//   f16x4 V-frags (b64 LDS reads). Pl buffer + 16 ds_write_b16 + lgkm
//   round-trip deleted from the per-period critical chain. LDS 16KB.
// - gemm_out on the R7 f16 path; cvt(Cp->Ct) restored; out-zero in cvt_all.

typedef _Float16 f16;
typedef _Float16 f16x4 __attribute__((ext_vector_type(4)));
typedef _Float16 f16x8 __attribute__((ext_vector_type(8)));
typedef float    f32x4 __attribute__((ext_vector_type(4)));

#define S_LEN 2048
#define DIM   1024
#define NH    16
#define DK    64
// exp(s * 0.125) = exp2(s * log2(e)/8)
#define EXP2K 0.1803368801111244f

#define MFMA(a, b, c)   __builtin_amdgcn_mfma_f32_16x16x32_f16(a, b, c, 0, 0, 0)
#define MFMA16(a, b, c) __builtin_amdgcn_mfma_f32_16x16x16f16(a, b, c, 0, 0, 0)

#define VM_WAIT0   asm volatile("s_waitcnt vmcnt(0)" ::: "memory")
#define WG_BARRIER asm volatile("s_barrier" ::: "memory")

typedef __attribute__((address_space(1))) void g_void;
typedef __attribute__((address_space(3))) void l_void;

static __device__ __forceinline__ void gload_lds16(const void* g, void* l) {
  __builtin_amdgcn_global_load_lds((g_void*)g, (l_void*)l, 16, 0, 0);
}

static __device__ __forceinline__ float exp_s(float s) {
  return __builtin_amdgcn_exp2f(s * EXP2K);
}

// ---------------------------------------------------------------- merged cvt + out-zero
__global__ __launch_bounds__(256) void cvt_all(
    const float* __restrict__ q, const float* __restrict__ k, const float* __restrict__ v,
    const float* __restrict__ Wq, const float* __restrict__ Wk, const float* __restrict__ Wv,
    const float* __restrict__ Wo, f16* __restrict__ qh, f16* __restrict__ kh,
    f16* __restrict__ vh, f16* __restrict__ wqh, f16* __restrict__ wkh,
    f16* __restrict__ wvh, f16* __restrict__ woh, float* __restrict__ outz) {
  const size_t M = 1048576;
  const int seg = blockIdx.y;
  int i = blockIdx.x * 256 + threadIdx.x;
  if (seg >= 10) {  // zero d_out
    float4 z4 = {0.f, 0.f, 0.f, 0.f};
    ((float4*)(outz + (size_t)(seg - 10) * M))[i] = z4;
    return;
  }
  const float* src;
  f16* dst;
  switch (seg) {
    case 0: src = q;      dst = qh;      break;
    case 1: src = q + M;  dst = qh + M;  break;
    case 2: src = k;      dst = kh;      break;
    case 3: src = k + M;  dst = kh + M;  break;
    case 4: src = v;      dst = vh;      break;
    case 5: src = v + M;  dst = vh + M;  break;
    case 6: src = Wq;     dst = wqh;     break;
    case 7: src = Wk;     dst = wkh;     break;
    case 8: src = Wv;     dst = wvh;     break;
    default: src = Wo;    dst = woh;     break;
  }
  float4 vv = ((const float4*)src)[i];
  f16x4 o = {(f16)vv.x, (f16)vv.y, (f16)vv.z, (f16)vv.w};
  ((f16x4*)dst)[i] = o;
}

__global__ __launch_bounds__(256) void cvt_f32_f16(const float* __restrict__ src,
                                                   f16* __restrict__ dst, int n4) {
  int i = blockIdx.x * 256 + threadIdx.x;
  if (i < n4) {
    float4 v = ((const float4*)src)[i];
    f16x4 o = {(f16)v.x, (f16)v.y, (f16)v.z, (f16)v.w};
    ((f16x4*)dst)[i] = o;
  }
}

// ---------------------------------------------------------------- pipelined 128x64 GEMM core
// BK=32 double-buffered (R7). 3 DMA + 8 MFMA per wave-period.
static __device__ __forceinline__ void gemm32_core(const f16* __restrict__ X,
                                                   const f16* __restrict__ W,
                                                   int k0, int k1, int bm, int bn,
                                                   f16* As, f16* Bs,
                                                   f32x4 (&acc)[4][2]) {
  const int tid = threadIdx.x;
  const int wv = tid >> 6;
  const int lane = tid & 63;
  const int qd = lane >> 4;
  const int l16 = lane & 15;
  const int wm = (wv & 1) * 64;
  const int wn = (wv >> 1) * 32;
  const int lr4 = lane >> 2, lc4 = lane & 3;

  const f16* gA = X + (size_t)(bm + wv * 32 + lr4) * DIM + k0 + lc4 * 8;
  const f16* gB = W + (size_t)(bn + wv * 16 + lr4) * DIM + k0 + lc4 * 8;
  const int np = (k1 - k0) >> 5;

  gload_lds16(gA, As + (wv * 32) * 32);
  gload_lds16(gA + 16 * DIM, As + (wv * 32 + 16) * 32);
  gload_lds16(gB, Bs + (wv * 16) * 32);

#pragma unroll 2
  for (int t = 0; t < np; t++) {
    const int buf = t & 1;
    VM_WAIT0;
    WG_BARRIER;
    if (t + 1 < np) {
      const f16* gA1 = gA + (t + 1) * 32;
      const f16* gB1 = gB + (t + 1) * 32;
      f16* dA = As + (buf ^ 1) * (128 * 32);
      f16* dB = Bs + (buf ^ 1) * (64 * 32);
      gload_lds16(gA1, dA + (wv * 32) * 32);
      gload_lds16(gA1 + 16 * DIM, dA + (wv * 32 + 16) * 32);
      gload_lds16(gB1, dB + (wv * 16) * 32);
    }
    const f16* A = As + buf * (128 * 32);
    const f16* B = Bs + buf * (64 * 32);
    f16x8 bf[2];
#pragma unroll
    for (int ni = 0; ni < 2; ni++)
      bf[ni] = *(const f16x8*)&B[(wn + ni * 16 + l16) * 32 + qd * 8];
#pragma unroll
    for (int mi = 0; mi < 4; mi++) {
      f16x8 af = *(const f16x8*)&A[(wm + mi * 16 + l16) * 32 + qd * 8];
#pragma unroll
      for (int ni = 0; ni < 2; ni++)
        acc[mi][ni] = MFMA(af, bf[ni], acc[mi][ni]);
    }
  }
}

// ---------------------------------------------------------------- merged QKV proj
__global__ __launch_bounds__(256) void gemm_qkv(
    const f16* __restrict__ X0, const f16* __restrict__ X1, const f16* __restrict__ X2,
    const f16* __restrict__ W0, const f16* __restrict__ W1, const f16* __restrict__ W2,
    const float* __restrict__ b0, const float* __restrict__ b1, const float* __restrict__ b2,
    f16* __restrict__ o0, f16* __restrict__ o1, f16* __restrict__ o2) {
  __shared__ __align__(16) f16 As[2 * 128 * 32];
  __shared__ __align__(16) f16 Bs[2 * 64 * 32];
  const int z = blockIdx.z;
  const f16* X = z == 0 ? X0 : z == 1 ? X1 : X2;
  const f16* W = z == 0 ? W0 : z == 1 ? W1 : W2;
  const float* bias = z == 0 ? b0 : z == 1 ? b1 : b2;
  f16* outh = z == 0 ? o0 : z == 1 ? o1 : o2;

  const int bm = blockIdx.y * 128, bn = blockIdx.x * 64;
  f32x4 acc[4][2];
#pragma unroll
  for (int a = 0; a < 4; a++)
#pragma unroll
    for (int b = 0; b < 2; b++) acc[a][b] = (f32x4){0.f, 0.f, 0.f, 0.f};

  gemm32_core(X, W, 0, DIM, bm, bn, As, Bs, acc);

  const int tid = threadIdx.x;
  const int wv = tid >> 6, lane = tid & 63;
  const int qd = lane >> 4, l16 = lane & 15;
  const int wm = (wv & 1) * 64, wn = (wv >> 1) * 32;
#pragma unroll
  for (int mi = 0; mi < 4; mi++) {
#pragma unroll
    for (int ni = 0; ni < 2; ni++) {
      const int gm = bm + wm + mi * 16 + qd * 4;
      const int gn = bn + wn + ni * 16 + l16;
      const float bs = bias[gn];
      if (z == 2) {
        f16x4 o = {(f16)(acc[mi][ni][0] + bs), (f16)(acc[mi][ni][1] + bs),
                   (f16)(acc[mi][ni][2] + bs), (f16)(acc[mi][ni][3] + bs)};
        *(f16x4*)&outh[(size_t)gn * S_LEN + gm] = o;  // Vt[d][j]
      } else {
#pragma unroll
        for (int r = 0; r < 4; r++)
          outh[(size_t)(gm + r) * DIM + gn] = (f16)(acc[mi][ni][r] + bs);
      }
    }
  }
}

// ---------------------------------------------------------------- out GEMM (R7 f16 path)
__global__ __launch_bounds__(256) void gemm_out(const f16* __restrict__ X,
                                                const f16* __restrict__ W,
                                                const float* __restrict__ bias,
                                                float* __restrict__ outf) {
  __shared__ __align__(16) f16 As[2 * 128 * 32];
  __shared__ __align__(16) f16 Bs[2 * 64 * 32];
  const int z = blockIdx.z;
  const int bm = blockIdx.y * 128, bn = blockIdx.x * 64;
  f32x4 acc[4][2];
#pragma unroll
  for (int a = 0; a < 4; a++)
#pragma unroll
    for (int b = 0; b < 2; b++) acc[a][b] = (f32x4){0.f, 0.f, 0.f, 0.f};

  gemm32_core(X, W, z * (DIM / 2), (z + 1) * (DIM / 2), bm, bn, As, Bs, acc);

  const int tid = threadIdx.x;
  const int wv = tid >> 6, lane = tid & 63;
  const int qd = lane >> 4, l16 = lane & 15;
  const int wm = (wv & 1) * 64, wn = (wv >> 1) * 32;
#pragma unroll
  for (int mi = 0; mi < 4; mi++) {
#pragma unroll
    for (int ni = 0; ni < 2; ni++) {
      const int gm = bm + wm + mi * 16 + qd * 4;
      const int gn = bn + wn + ni * 16 + l16;
      const float bs = z == 0 ? bias[gn] : 0.f;
#pragma unroll
      for (int r = 0; r < 4; r++)
        atomicAdd(&outf[(size_t)(gm + r) * DIM + gn], acc[mi][ni][r] + bs);
    }
  }
}

// ---------------------------------------------------------------- pass A: IDn = 1/sum_h exp
// R7 version: 64x64 tile, grid (32,32)=1024, double-buffer, unroll 2.
__global__ __launch_bounds__(256) void attn_denom(const f16* __restrict__ Qp,
                                                  const f16* __restrict__ Kp,
                                                  f16* __restrict__ IDn) {
  __shared__ __align__(16) f16 Qs[2][2][64 * 32];  // [buf][kk][row][32]
  __shared__ __align__(16) f16 Ks[2][2][64 * 32];
  const int tid = threadIdx.x;
  const int wv = tid >> 6;
  const int lane = tid & 63;
  const int qd = lane >> 4;
  const int l16 = lane & 15;
  const int wm = (wv & 1) * 32, wn = (wv >> 1) * 32;
  const int bi = blockIdx.y * 64, bj = blockIdx.x * 64;
  const int lr4 = lane >> 2, lc4 = lane & 3;
  const int kkw = wv & 1;
  const int q0 = (wv >> 1) * 2;

  f32x4 dsum[2][2];
#pragma unroll
  for (int a = 0; a < 2; a++)
#pragma unroll
    for (int b = 0; b < 2; b++) dsum[a][b] = (f32x4){0.f, 0.f, 0.f, 0.f};

  {
    const f16* gq = Qp + (size_t)(bi + q0 * 16 + lr4) * DIM + kkw * 32 + lc4 * 8;
    const f16* gk = Kp + (size_t)(bj + q0 * 16 + lr4) * DIM + kkw * 32 + lc4 * 8;
#pragma unroll
    for (int t = 0; t < 2; t++) {
      gload_lds16(gq + (size_t)t * 16 * DIM, &Qs[0][kkw][(q0 + t) * 16 * 32]);
      gload_lds16(gk + (size_t)t * 16 * DIM, &Ks[0][kkw][(q0 + t) * 16 * 32]);
    }
  }

#pragma unroll 2
  for (int h = 0; h < NH; h++) {
    const int buf = h & 1;
    VM_WAIT0;
    WG_BARRIER;
    if (h + 1 < NH) {
      const f16* gq = Qp + (size_t)(bi + q0 * 16 + lr4) * DIM + (h + 1) * DK + kkw * 32 + lc4 * 8;
      const f16* gk = Kp + (size_t)(bj + q0 * 16 + lr4) * DIM + (h + 1) * DK + kkw * 32 + lc4 * 8;
#pragma unroll
      for (int t = 0; t < 2; t++) {
        gload_lds16(gq + (size_t)t * 16 * DIM, &Qs[buf ^ 1][kkw][(q0 + t) * 16 * 32]);
        gload_lds16(gk + (size_t)t * 16 * DIM, &Ks[buf ^ 1][kkw][(q0 + t) * 16 * 32]);
      }
    }

#pragma unroll
    for (int mi = 0; mi < 2; mi++) {
      f16x8 af0 = *(const f16x8*)&Qs[buf][0][(wm + mi * 16 + l16) * 32 + qd * 8];
      f16x8 af1 = *(const f16x8*)&Qs[buf][1][(wm + mi * 16 + l16) * 32 + qd * 8];
#pragma unroll
      for (int ni = 0; ni < 2; ni++) {
        f16x8 bf0 = *(const f16x8*)&Ks[buf][0][(wn + ni * 16 + l16) * 32 + qd * 8];
        f16x8 bf1 = *(const f16x8*)&Ks[buf][1][(wn + ni * 16 + l16) * 32 + qd * 8];
        f32x4 s = {0.f, 0.f, 0.f, 0.f};
        s = MFMA(af0, bf0, s);
        s = MFMA(af1, bf1, s);
#pragma unroll
        for (int r = 0; r < 4; r++) dsum[mi][ni][r] += exp_s(s[r]);
      }
    }
  }
#pragma unroll
  for (int mi = 0; mi < 2; mi++)
#pragma unroll
    for (int ni = 0; ni < 2; ni++)
#pragma unroll
      for (int r = 0; r < 4; r++) {
        const int gi = bi + wm + mi * 16 + qd * 4 + r;
        const int gj = bj + wn + ni * 16 + l16;
        IDn[(size_t)gi * S_LEN + gj] = (f16)(1.f / dsum[mi][ni][r]);
      }
}

// ---------------------------------------------------------------- pass B: ctx
// grid (S/128, NH, 4). Wave = 32 i-rows, 16x 32-j periods, K/V double-buffered
// LDS-DMA + pipelined. S computed TRANSPOSED: st = mfma(A=K, B=Q) -> lane holds
// (j=qd*4+r, i=l16) = A-layout of the K=16 MFMA. P = (f16)(exp*IDn) in regs;
// PV via K=16 MFMA with f16x4 V-frags. No P LDS traffic. LDS 16KB.
__global__ __launch_bounds__(256, 4) void attn_ctx(const f16* __restrict__ Qp,
                                                   const f16* __restrict__ Kp,
                                                   const f16* __restrict__ Vt,
                                                   const f16* __restrict__ IDn,
                                                   float* __restrict__ Cp) {
  __shared__ __align__(16) f16 Ks[2][2][32 * 32];  // [buf][kk][j][k32]
  __shared__ __align__(16) f16 Vs[2][64 * 32];     // [buf][d][j32]
  const int tid = threadIdx.x;
  const int wv = tid >> 6;
  const int lane = tid & 63;
  const int qd = lane >> 4;
  const int l16 = lane & 15;
  const int h = blockIdx.y;
  const int i0 = blockIdx.x * 128;
  const int iw = i0 + wv * 32;
  const int jb = blockIdx.z * 512;
  const int lr4 = lane >> 2, lc4 = lane & 3;
  const int kkw = wv & 1;
  const int rhw = wv >> 1;

  // persistent Q fragments (now the MFMA B-operand; same registers as before)
  f16x8 aq[2][2];
#pragma unroll
  for (int mi = 0; mi < 2; mi++)
#pragma unroll
    for (int kk = 0; kk < 2; kk++)
      aq[mi][kk] = *(const f16x8*)(Qp + (size_t)(iw + mi * 16 + l16) * DIM +
                                   h * DK + kk * 32 + qd * 8);

  f32x4 acc[2][4];
#pragma unroll
  for (int a = 0; a < 2; a++)
#pragma unroll
    for (int b = 0; b < 4; b++) acc[a][b] = (f32x4){0.f, 0.f, 0.f, 0.f};

  // IDn in st-layout: lane (i = iw+mi*16+l16, j = j0+ni*16+qd*4..+3) -> f16x4
  f16x4 idn[2][2][2];  // [buf][mi][ni]

  {
    const int j0 = jb;
    gload_lds16(Kp + (size_t)(j0 + rhw * 16 + lr4) * DIM + h * DK + kkw * 32 + lc4 * 8,
                &Ks[0][kkw][(rhw * 16) * 32]);
    gload_lds16(Vt + (size_t)(h * DK + wv * 16 + lr4) * S_LEN + j0 + lc4 * 8,
                &Vs[0][(wv * 16) * 32]);
#pragma unroll
    for (int mi = 0; mi < 2; mi++)
#pragma unroll
      for (int ni = 0; ni < 2; ni++)
        idn[0][mi][ni] = *(const f16x4*)(IDn + (size_t)(iw + mi * 16 + l16) * S_LEN +
                                         j0 + ni * 16 + qd * 4);
  }

#pragma unroll 2
  for (int jt = 0; jt < 16; jt++) {
    const int buf = jt & 1;
    VM_WAIT0;
    WG_BARRIER;

    if (jt + 1 < 16) {
      const int j1 = jb + (jt + 1) * 32;
      gload_lds16(Kp + (size_t)(j1 + rhw * 16 + lr4) * DIM + h * DK + kkw * 32 + lc4 * 8,
                  &Ks[buf ^ 1][kkw][(rhw * 16) * 32]);
      gload_lds16(Vt + (size_t)(h * DK + wv * 16 + lr4) * S_LEN + j1 + lc4 * 8,
                  &Vs[buf ^ 1][(wv * 16) * 32]);
#pragma unroll
      for (int mi = 0; mi < 2; mi++)
#pragma unroll
        for (int ni = 0; ni < 2; ni++)
          idn[buf ^ 1][mi][ni] = *(const f16x4*)(IDn + (size_t)(iw + mi * 16 + l16) * S_LEN +
                                                 j1 + ni * 16 + qd * 4);
    }

    // K fragments (A-operand): lane = j-row, regs = k
    f16x8 bk[2][2];
#pragma unroll
    for (int ni = 0; ni < 2; ni++)
#pragma unroll
      for (int kk = 0; kk < 2; kk++)
        bk[ni][kk] = *(const f16x8*)&Ks[buf][kk][(ni * 16 + l16) * 32 + qd * 8];

#pragma unroll
    for (int ni = 0; ni < 2; ni++) {
      // V fragments for this 16-j window: B[n=d][k=j], f16x4 (k=16)
      f16x4 bv[4];
#pragma unroll
      for (int nd = 0; nd < 4; nd++)
        bv[nd] = *(const f16x4*)&Vs[buf][(nd * 16 + l16) * 32 + ni * 16 + qd * 4];
#pragma unroll
      for (int mi = 0; mi < 2; mi++) {
        f32x4 st = {0.f, 0.f, 0.f, 0.f};
        st = MFMA(bk[ni][0], aq[mi][0], st);  // S^T: A=K, B=Q
        st = MFMA(bk[ni][1], aq[mi][1], st);
        f16x4 p;
#pragma unroll
        for (int r = 0; r < 4; r++)
          p[r] = (f16)(exp_s(st[r]) * (float)idn[buf][mi][ni][r]);
#pragma unroll
        for (int nd = 0; nd < 4; nd++)
          acc[mi][nd] = MFMA16(p, bv[nd], acc[mi][nd]);
      }
    }
  }

#pragma unroll
  for (int mi = 0; mi < 2; mi++)
#pragma unroll
    for (int nd = 0; nd < 4; nd++)
#pragma unroll
      for (int r = 0; r < 4; r++)
        atomicAdd(&Cp[(size_t)(iw + mi * 16 + qd * 4 + r) * DIM + h * DK + nd * 16 + l16],
                  acc[mi][nd][r]);
}

// ---------------------------------------------------------------- launcher
extern "C" void kernel_launch(void* const* d_in, const int* in_sizes, int n_in,
                              void* d_out, int out_size, void* d_ws, size_t ws_size,
                              hipStream_t stream) {
  const float* q  = (const float*)d_in[0];
  const float* k  = (const float*)d_in[1];
  const float* v  = (const float*)d_in[2];
  const float* Wq = (const float*)d_in[3];
  const float* bq = (const float*)d_in[4];
  const float* Wk = (const float*)d_in[5];
  const float* bk = (const float*)d_in[6];
  const float* Wv = (const float*)d_in[7];
  const float* bv = (const float*)d_in[8];
  const float* Wo = (const float*)d_in[9];
  const float* bo = (const float*)d_in[10];
  float* out = (float*)d_out;

  f16* w = (f16*)d_ws;
  f16* qh  = w;                          // 0..4MB
  f16* kh  = qh + (size_t)S_LEN * DIM;   // 4..8
  f16* vh  = kh + (size_t)S_LEN * DIM;   // 8..12
  f16* wqh = vh + (size_t)S_LEN * DIM;   // 12..14
  f16* wkh = wqh + (size_t)DIM * DIM;    // 14..16
  f16* wvh = wkh + (size_t)DIM * DIM;    // 16..18
  f16* woh = wvh + (size_t)DIM * DIM;    // 18..20
  f16* Qp  = woh + (size_t)DIM * DIM;    // 20..24
  f16* Kp  = Qp + (size_t)S_LEN * DIM;   // 24..28
  f16* Vt  = Kp + (size_t)S_LEN * DIM;   // 28..32
  f16* IDn = qh;                         // 0..8MB  [qh/kh dead after gemm_qkv]
  float* Cp = (float*)vh;                // 8..16MB [vh/wqh/wkh dead after gemm_qkv]
  f16* Ct  = qh;                         // 0..4MB  [IDn dead after attn_ctx]

  dim3 b256(256);
  cvt_all<<<dim3(1024, 12), b256, 0, stream>>>(q, k, v, Wq, Wk, Wv, Wo,
                                               qh, kh, vh, wqh, wkh, wvh, woh, out);

  gemm_qkv<<<dim3(DIM / 64, S_LEN / 128, 3), b256, 0, stream>>>(
      qh, kh, vh, wqh, wkh, wvh, bq, bk, bv, Qp, Kp, Vt);

  hipMemsetAsync(Cp, 0, (size_t)S_LEN * DIM * sizeof(float), stream);

  attn_denom<<<dim3(S_LEN / 64, S_LEN / 64), b256, 0, stream>>>(Qp, Kp, IDn);
  attn_ctx<<<dim3(S_LEN / 128, NH, 4), b256, 0, stream>>>(Qp, Kp, Vt, IDn, Cp);

  const int nqkv4 = S_LEN * DIM / 4;
  cvt_f32_f16<<<nqkv4 / 256, b256, 0, stream>>>(Cp, Ct, nqkv4);

  gemm_out<<<dim3(DIM / 64, S_LEN / 128, 2), b256, 0, stream>>>(Ct, woh, bo, out);
}